// Round 7
// baseline (703.469 us; speedup 1.0000x reference)
//
#include <hip/hip_runtime.h>
#include <hip/hip_fp16.h>
#include <hip/hip_cooperative_groups.h>

namespace cg = cooperative_groups;

#define Nn 50000
#define Ee 800000
#define Tt 12
#define NBAND 8
#define BAND 6250        // Nn / NBAND exactly
#define CAP 64           // fixed adj slots per node; P(Poisson(16) >= 64) ~ 8e-20
#define NCHUNK ((Nn * 8 + 255) / 256)   // 1563 gather chunks
#define NWI ((Nn + 31) / 32)            // 1563 step2 work items
// HID=128, K=3, F_IN=7, effective features = 35 (+1 bias slot)
// Node feature rows: 8 x f16 = 16 B (one dwordx4 gather).
// adj entry (4 B): (peer << 16) | f16(w).  adjR keyed by r (peer=c), adjC by c.
//
// Session ledger (counter-verified lessons):
//  r1: nontemporal hints on scatter -> no change. WRITE_SIZE on atomic kernels
//      is coherent-point RMW traffic, not line eviction.
//  r2: 1.6M global RMWs == ~68us regardless of access pattern; csr_direct
//      (3.2M RMWs, 70us) sits at the same fabric rate. CSR build is done.
//  r3: 16-block LDS-scan scatter -> 210us (0.7% occupancy). Never again.
//  r4: k-outer phase B -> +52us (serialized weight loads vs FMAs). Keep the
//      per-wave wz[36]/wh[36] register form.
//  r5: slotted CSR (start = node<<6, one kernel): 791 -> 730us.
//  r6: branchless gather6: -30us only -> loop is NOT latency-chain bound.
//      In-kernel budgets sum to ~20-25us/step vs 52 measured; the residual
//      tracks the 2 dispatch boundaries/step.
//  r7 (this): cooperative mega-kernel, 23 grid.sync() replace 23 launch gaps;
//      work-stealing for load balance; clean fallback to the r6 loop.

// ====== csr_direct: banded direct-slot scatter, the whole CSR build ========
__global__ __launch_bounds__(256) void csr_direct(
    const int* __restrict__ ei, const float* __restrict__ ew,
    int* __restrict__ nextR, int* __restrict__ nextC,
    unsigned* __restrict__ adjR, unsigned* __restrict__ adjC)
{
    int band = blockIdx.x & (NBAND - 1);
    int chunk = blockIdx.x >> 3;
    int lo = band * BAND, hi = lo + BAND;
    int stride = (gridDim.x >> 3) * 256;
    for (int e = chunk * 256 + threadIdx.x; e < Ee; e += stride) {
        int r = ei[e], c = ei[Ee + e];
        bool br = (r >= lo) & (r < hi);
        bool bc = (c >= lo) & (c < hi);
        if (br | bc) {
            unsigned wb = __half_as_ushort(__float2half(ew[e]));
            if (br) adjR[(r << 6) + atomicAdd(&nextR[r], 1)] = ((unsigned)c << 16) | wb;
            if (bc) adjC[(c << 6) + atomicAdd(&nextC[c], 1)] = ((unsigned)r << 16) | wb;
        }
    }
}

// ==== effective weights, layout [gate][k*128 + j], k=35 is the bias row ====
// f layout: [0..6]=X, [7..13]=Tx_o, [14..20]=Tx_i, [21..27]=T2_o, [28..34]=T2_i, [35]=1
__global__ __launch_bounds__(256) void weff_kernel(
    const float* __restrict__ Wz, const float* __restrict__ Wh,
    const float* __restrict__ bz, const float* __restrict__ bh,
    float* __restrict__ wzT, float* __restrict__ whT)
{
    int idx = blockIdx.x * 256 + threadIdx.x;
    if (idx >= 2 * 36 * 128) return;
    const float* W = (idx < 36 * 128) ? Wz : Wh;
    const float* B = (idx < 36 * 128) ? bz : bh;
    float* O       = (idx < 36 * 128) ? wzT : whT;
    int rem = idx % (36 * 128);
    int k = rem / 128, j = rem % 128;
    float v;
    if (k == 35) v = B[j];
    else {
        int p = k / 7, rr = k % 7;
        // W flat: ((d*3 + kk)*135 + rr)*128 + j
        if (p == 0)      v = W[(0 * 135 + rr) * 128 + j] + W[(3 * 135 + rr) * 128 + j];
        else if (p == 1) v = W[(1 * 135 + rr) * 128 + j];
        else if (p == 2) v = W[(4 * 135 + rr) * 128 + j];
        else if (p == 3) v = W[(2 * 135 + rr) * 128 + j];
        else             v = W[(5 * 135 + rr) * 128 + j];
    }
    O[k * 128 + j] = v;
}

// =================== init: Xh row (f16) and out column 0 ===================
__global__ __launch_bounds__(256) void init_kernel(
    const float* __restrict__ x, const float* __restrict__ env,
    const float* __restrict__ coords, __half* __restrict__ Xh,
    float* __restrict__ out)
{
    int i = blockIdx.x * 256 + threadIdx.x;
    if (i >= Nn) return;
    float xv = x[i * Tt];
    __half* r = Xh + (long)i * 8;
    r[0] = __float2half(xv);
    #pragma unroll
    for (int c = 0; c < 4; c++) r[1 + c] = __float2half(env[i * 48 + c * 12]);
    r[5] = __float2half(coords[i * 2 + 0]);
    r[6] = __float2half(coords[i * 2 + 1]);
    r[7] = __half(0.f);
    out[i * 13 + 0] = xv;
}

__device__ __forceinline__ void unpack8(const __half* p, float* v) {
    uint4 hv = *((const uint4*)p);
    float2 p0 = __half22float2(*(__half2*)&hv.x);
    float2 p1 = __half22float2(*(__half2*)&hv.y);
    float2 p2 = __half22float2(*(__half2*)&hv.z);
    float2 p3 = __half22float2(*(__half2*)&hv.w);
    v[0] = p0.x; v[1] = p0.y; v[2] = p1.x; v[3] = p1.y;
    v[4] = p2.x; v[5] = p2.y; v[6] = p3.x;
}

__device__ __forceinline__ void pack8(__half* p, const float* v) {
    __half2 q0 = __floats2half2_rn(v[0], v[1]);
    __half2 q1 = __floats2half2_rn(v[2], v[3]);
    __half2 q2 = __floats2half2_rn(v[4], v[5]);
    __half2 q3 = __floats2half2_rn(v[6], 0.f);
    uint4 st;
    st.x = *(unsigned*)&q0; st.y = *(unsigned*)&q1;
    st.z = *(unsigned*)&q2; st.w = *(unsigned*)&q3;
    *((uint4*)p) = st;
}

// accumulate a[0..6] += w * halfrow(hv)
__device__ __forceinline__ void acc7(float* a, float w, uint4 hv) {
    float2 p0 = __half22float2(*(__half2*)&hv.x);
    float2 p1 = __half22float2(*(__half2*)&hv.y);
    float2 p2 = __half22float2(*(__half2*)&hv.z);
    float2 p3 = __half22float2(*(__half2*)&hv.w);
    a[0] = fmaf(w, p0.x, a[0]); a[1] = fmaf(w, p0.y, a[1]);
    a[2] = fmaf(w, p1.x, a[2]); a[3] = fmaf(w, p1.y, a[3]);
    a[4] = fmaf(w, p2.x, a[4]); a[5] = fmaf(w, p2.y, a[5]);
    a[6] = fmaf(w, p3.x, a[6]);
}

__device__ __forceinline__ float wdec(unsigned ed) {
    return __half2float(__ushort_as_half((unsigned short)(ed & 0xffffu)));
}

// Branchless fixed-depth gather core (r6, kept): 6 slots stride 4 covers
// deg<=24 in one latency exposure; rare fallback loop beyond.
__device__ __forceinline__ void gather6(
    const unsigned* __restrict__ adj, const __half* __restrict__ src,
    int b, int k0, int e, float* a, float* sw)
{
    unsigned en[6];
    bool v[6];
    #pragma unroll
    for (int s = 0; s < 6; s++) {
        int k = k0 + 4 * s;
        v[s] = k < e;
        en[s] = adj[v[s] ? k : b];
    }
    uint4 rv[6];
    #pragma unroll
    for (int s = 0; s < 6; s++)
        rv[s] = *(const uint4*)(src + (long)(v[s] ? (en[s] >> 16) : 0u) * 8);
    #pragma unroll
    for (int s = 0; s < 6; s++) {
        float w = v[s] ? wdec(en[s]) : 0.f;
        acc7(a, w, rv[s]);
        if (sw) *sw += w;
    }
    for (int k = k0 + 24; k < e; k += 4) {    // rare: deg > 24
        unsigned ed = adj[k];
        uint4 r2 = *(const uint4*)(src + (long)(ed >> 16) * 8);
        float w = wdec(ed);
        acc7(a, w, r2);
        if (sw) *sw += w;
    }
}

// =============== phase bodies (shared by mega-kernel and fallback) =========
__device__ __forceinline__ void gather_phase(
    int tid,
    const int* __restrict__ cntR, const unsigned* __restrict__ adjR,
    const int* __restrict__ cntC, const unsigned* __restrict__ adjC,
    const __half* __restrict__ Xh,
    __half* __restrict__ TxoH, __half* __restrict__ TxiH,
    float* __restrict__ inv_out, float* __restrict__ inv_in)
{
    int node = tid >> 3;
    int dir = (tid >> 2) & 1, sub = tid & 3;
    const int*      cn  = dir ? cntC : cntR;
    const unsigned* adj = dir ? adjC : adjR;
    int b = node << 6, e = b + cn[node];
    float a[7] = {0.f, 0.f, 0.f, 0.f, 0.f, 0.f, 0.f};
    float sw = 0.f;
    gather6(adj, Xh, b, b + sub, e, a, &sw);
    #pragma unroll
    for (int m = 1; m <= 2; m <<= 1) {
        #pragma unroll
        for (int q = 0; q < 7; q++) a[q] += __shfl_xor(a[q], m);
        sw += __shfl_xor(sw, m);
    }
    if (sub == 0) {
        float inv = sw > 0.f ? 1.f / sw : 0.f;
        (dir ? inv_in : inv_out)[node] = inv;
        #pragma unroll
        for (int q = 0; q < 7; q++) a[q] *= inv;
        pack8((dir ? TxiH : TxoH) + (long)node * 8, a);
    }
}

__device__ __forceinline__ void step_phase(
    int wi, int t,
    const int* __restrict__ cntR, const unsigned* __restrict__ adjR,
    const int* __restrict__ cntC, const unsigned* __restrict__ adjC,
    const float* __restrict__ inv_out, const float* __restrict__ inv_in,
    const float* __restrict__ env, const float* __restrict__ night,
    const float* __restrict__ wzT, const float* __restrict__ whT,
    const float* __restrict__ linW, const float* __restrict__ linb,
    __half* __restrict__ Xh,
    const __half* __restrict__ TxoH, const __half* __restrict__ TxiH,
    float* __restrict__ out)
{
    __shared__ float f_s[32][36];
    __shared__ float part_s[2][32];
    int tid = threadIdx.x;
    int base = wi * 32;

    // ---- phase A: T2 for this item's 32 nodes, straight into LDS ----
    {
        int nl = tid >> 3;
        int dir = (tid >> 2) & 1, sub = tid & 3;
        int node = base + nl;
        int nc = node < Nn ? node : Nn - 1;   // clamp; output stores guarded
        const int*      cn  = dir ? cntC : cntR;
        const unsigned* adj = dir ? adjC : adjR;
        const __half*   src = dir ? TxiH : TxoH;
        int b = nc << 6, e = b + cn[nc];
        float a[7] = {0.f, 0.f, 0.f, 0.f, 0.f, 0.f, 0.f};
        gather6(adj, src, b, b + sub, e, a, nullptr);
        #pragma unroll
        for (int m = 1; m <= 2; m <<= 1) {
            #pragma unroll
            for (int q = 0; q < 7; q++) a[q] += __shfl_xor(a[q], m);
        }
        if (sub == 0) {
            float s2 = 2.f * (dir ? inv_in[nc] : inv_out[nc]);
            float xv[7], tx[7];
            unpack8(Xh + (long)nc * 8, xv);
            unpack8(src + (long)nc * 8, tx);     // own Tx row (dir-matched)
            #pragma unroll
            for (int q = 0; q < 7; q++) {
                f_s[nl][21 + 7 * dir + q] = fmaf(s2, a[q], -xv[q]);
                f_s[nl][7 + 7 * dir + q]  = tx[q];
            }
            if (dir == 0) {
                #pragma unroll
                for (int q = 0; q < 7; q++) f_s[nl][q] = xv[q];
                f_s[nl][35] = 1.f;
            }
        }
    }
    __syncthreads();

    // ---- phase B: dense 36x128x2 contraction + activations + output ----
    int lane = tid & 63;
    int wave = tid >> 6;
    int chSel = wave & 1;
    int ch = chSel * 64 + lane;
    int half_id = wave >> 1;
    float wz[36], wh[36];
    #pragma unroll
    for (int k = 0; k < 36; k++) wz[k] = wzT[k * 128 + ch];
    #pragma unroll
    for (int k = 0; k < 36; k++) wh[k] = whT[k * 128 + ch];
    float lw = linW[ch];
    float lb = linb[0];

    #pragma unroll 1
    for (int n = 0; n < 16; n++) {
        int ni = half_id * 16 + n;
        const float4* fv = (const float4*)f_s[ni];   // broadcast reads
        float hz = 0.f, hh = 0.f;
        #pragma unroll
        for (int q = 0; q < 9; q++) {
            float4 fq = fv[q];
            hz = fmaf(fq.x, wz[q*4+0], hz); hh = fmaf(fq.x, wh[q*4+0], hh);
            hz = fmaf(fq.y, wz[q*4+1], hz); hh = fmaf(fq.y, wh[q*4+1], hh);
            hz = fmaf(fq.z, wz[q*4+2], hz); hh = fmaf(fq.z, wh[q*4+2], hh);
            hz = fmaf(fq.w, wz[q*4+3], hz); hh = fmaf(fq.w, wh[q*4+3], hh);
        }
        float z  = 1.f / (1.f + __expf(-hz));
        float e2 = __expf(2.f * hh);
        float ht = 1.f - 2.f / (e2 + 1.f);           // tanh
        float v = fmaxf((1.f - z) * ht, 0.f) * lw;   // (1-Z)*H~, relu, lin
        v += __shfl_xor(v, 1);  v += __shfl_xor(v, 2);  v += __shfl_xor(v, 4);
        v += __shfl_xor(v, 8);  v += __shfl_xor(v, 16); v += __shfl_xor(v, 32);
        if (lane == 0) part_s[chSel][ni] = v;
    }
    __syncthreads();
    if (tid < 32) {
        int node = base + tid;
        if (node < Nn) {
            float o = part_s[0][tid] + part_s[1][tid] + lb;
            o *= night[(long)node * 13 + t + 1];
            out[(long)node * 13 + t + 1] = o;
            if (t + 1 < Tt) {
                __half* xr = Xh + (long)node * 8;
                xr[0] = __float2half(o);
                #pragma unroll
                for (int c = 0; c < 4; c++)
                    xr[1 + c] = __float2half(env[(long)node * 48 + c * 12 + t + 1]);
            }
        }
    }
}

// ============ cooperative mega-kernel: all 12 steps, 23 grid syncs =========
// 4 blocks/CU guaranteed (launch_bounds 256,4 -> VGPR<=128); grid = 4*CUs.
// Work-stealing via ctr[t] (gather chunks) / ctr[12+t] (step2 items) removes
// the ceil(1563/grid) round-imbalance a plain grid-stride would have.
__global__ __launch_bounds__(256, 4) void loop_kernel(
    const int* __restrict__ cntR, const unsigned* __restrict__ adjR,
    const int* __restrict__ cntC, const unsigned* __restrict__ adjC,
    float* __restrict__ inv_out, float* __restrict__ inv_in,
    const float* __restrict__ env, const float* __restrict__ night,
    const float* __restrict__ wzT, const float* __restrict__ whT,
    const float* __restrict__ linW, const float* __restrict__ linb,
    __half* __restrict__ Xh, __half* __restrict__ TxoH, __half* __restrict__ TxiH,
    float* __restrict__ out, int* __restrict__ ctr)
{
    cg::grid_group grid = cg::this_grid();
    __shared__ int item_s;
    for (int t = 0; t < Tt; t++) {
        // ---- phase G: Tx gather over Nn*8 thread-items, 256 per chunk ----
        for (;;) {
            if (threadIdx.x == 0) item_s = atomicAdd(&ctr[t], 1);
            __syncthreads();
            int chunk = item_s;
            __syncthreads();              // all read before next overwrite
            if (chunk >= NCHUNK) break;   // uniform
            int tid = chunk * 256 + threadIdx.x;
            if (tid < Nn * 8)
                gather_phase(tid, cntR, adjR, cntC, adjC, Xh, TxoH, TxiH,
                             inv_out, inv_in);
        }
        __threadfence();
        grid.sync();
        // ---- phase S: T2 + dense over 1563 32-node items ----
        for (;;) {
            if (threadIdx.x == 0) item_s = atomicAdd(&ctr[12 + t], 1);
            __syncthreads();
            int wi = item_s;
            __syncthreads();
            if (wi >= NWI) break;         // uniform
            step_phase(wi, t, cntR, adjR, cntC, adjC, inv_out, inv_in,
                       env, night, wzT, whT, linW, linb, Xh, TxoH, TxiH, out);
        }
        __threadfence();
        grid.sync();
    }
}

// ================== fallback wrappers (r6 structure, proven) ===============
__global__ __launch_bounds__(256) void gather1_kernel(
    const int* __restrict__ cntR, const unsigned* __restrict__ adjR,
    const int* __restrict__ cntC, const unsigned* __restrict__ adjC,
    const __half* __restrict__ Xh,
    __half* __restrict__ TxoH, __half* __restrict__ TxiH,
    float* __restrict__ inv_out, float* __restrict__ inv_in)
{
    int tid = blockIdx.x * 256 + threadIdx.x;
    if (tid >= Nn * 8) return;
    gather_phase(tid, cntR, adjR, cntC, adjC, Xh, TxoH, TxiH, inv_out, inv_in);
}

__global__ __launch_bounds__(256) void step2_kernel(
    const int* __restrict__ cntR, const unsigned* __restrict__ adjR,
    const int* __restrict__ cntC, const unsigned* __restrict__ adjC,
    const float* __restrict__ inv_out, const float* __restrict__ inv_in,
    const float* __restrict__ env, const float* __restrict__ night,
    const float* __restrict__ wzT, const float* __restrict__ whT,
    const float* __restrict__ linW, const float* __restrict__ linb,
    __half* __restrict__ Xh,
    const __half* __restrict__ TxoH, const __half* __restrict__ TxiH,
    float* __restrict__ out, int t)
{
    step_phase(blockIdx.x, t, cntR, adjR, cntC, adjC, inv_out, inv_in,
               env, night, wzT, whT, linW, linb, Xh, TxoH, TxiH, out);
}

extern "C" void kernel_launch(void* const* d_in, const int* in_sizes, int n_in,
                              void* d_out, int out_size, void* d_ws, size_t ws_size,
                              hipStream_t stream) {
    const float* x      = (const float*)d_in[0];
    const float* env    = (const float*)d_in[1];
    const float* coords = (const float*)d_in[2];
    const int*   ei     = (const int*)d_in[3];
    const float* ew     = (const float*)d_in[4];
    const float* night  = (const float*)d_in[5];
    const float* Wz     = (const float*)d_in[6];
    const float* bz     = (const float*)d_in[7];
    // d_in[8]=Wr, d_in[9]=br unused (R gate never affects output)
    const float* Wh     = (const float*)d_in[10];
    const float* bh     = (const float*)d_in[11];
    const float* linW   = (const float*)d_in[12];
    const float* linb   = (const float*)d_in[13];
    float* out = (float*)d_out;

    float* w = (float*)d_ws;
    float* wzT     = w;                     // 36*128
    float* whT     = w + 4608;
    float* inv_out = w + 9216;              // N
    float* inv_in  = w + 59216;
    __half* Xh   = (__half*)(w + 109216);   // N x 8 halves (16B-aligned offsets)
    __half* TxoH = (__half*)(w + 309216);
    __half* TxiH = (__half*)(w + 509216);
    int* nextR   = (int*)(w + 709216);      // N; doubles as cntR after scatter
    int* nextC   = nextR + 50000;           // N; doubles as cntC
    int* ctr     = (int*)(w + 809216);      // 64 ints: [0..11]=G, [12..23]=S
    unsigned* adjR = (unsigned*)(w + 809280);    // N*64 slots x 4B = 12.8 MB
    unsigned* adjC = adjR + Nn * CAP;            // 12.8 MB; end ~ 28.8 MB

    // ---- CSR build: single direct-slot scatter + counter zeroing ----
    hipMemsetAsync(nextR, 0, (2 * Nn + 64) * sizeof(int), stream);
    csr_direct<<<8 * 256, 256, 0, stream>>>(ei, ew, nextR, nextC, adjR, adjC);

    weff_kernel<<<(2 * 36 * 128 + 255) / 256, 256, 0, stream>>>(Wz, Wh, bz, bh, wzT, whT);
    init_kernel<<<(Nn + 255) / 256, 256, 0, stream>>>(x, env, coords, Xh, out);

    // ---- time loop: cooperative mega-kernel, fallback to r6 loop ----
    static int coopGrid = -2;   // -2 uninit, -1 unavailable
    if (coopGrid == -2) {
        hipDeviceProp_t prop{};
        if (hipGetDeviceProperties(&prop, 0) == hipSuccess &&
            prop.cooperativeLaunch && prop.multiProcessorCount > 0) {
            coopGrid = 4 * prop.multiProcessorCount;       // launch_bounds(256,4)
            if (coopGrid > NWI) coopGrid = NWI;
        } else coopGrid = -1;
    }
    bool did_coop = false;
    if (coopGrid > 0) {
        void* params[] = { (void*)&nextR, (void*)&adjR, (void*)&nextC, (void*)&adjC,
                           (void*)&inv_out, (void*)&inv_in, (void*)&env, (void*)&night,
                           (void*)&wzT, (void*)&whT, (void*)&linW, (void*)&linb,
                           (void*)&Xh, (void*)&TxoH, (void*)&TxiH, (void*)&out,
                           (void*)&ctr };
        if (hipLaunchCooperativeKernel((const void*)loop_kernel, dim3(coopGrid),
                                       dim3(256), params, 0, stream) == hipSuccess)
            did_coop = true;
        else
            coopGrid = -1;   // don't retry on later calls
    }
    if (!did_coop) {
        for (int t = 0; t < Tt; t++) {
            gather1_kernel<<<(Nn * 8 + 255) / 256, 256, 0, stream>>>(
                nextR, adjR, nextC, adjC, Xh, TxoH, TxiH, inv_out, inv_in);
            step2_kernel<<<(Nn + 31) / 32, 256, 0, stream>>>(
                nextR, adjR, nextC, adjC, inv_out, inv_in,
                env, night, wzT, whT, linW, linb, Xh, TxoH, TxiH, out, t);
        }
    }
}

// Round 8
// 701.577 us; speedup vs baseline: 1.0027x; 1.0027x over previous
//
#include <hip/hip_runtime.h>
#include <hip/hip_fp16.h>
#include <hip/hip_cooperative_groups.h>

namespace cg = cooperative_groups;

#define Nn 50000
#define Ee 800000
#define Tt 12
#define NBAND 8
#define BAND 6250        // Nn / NBAND exactly
#define CAP 64           // fixed adj slots per node; P(Poisson(16) >= 64) ~ 8e-20
#define NCHUNK ((Nn * 8 + 255) / 256)   // 1563 gather chunks
#define NWI ((Nn + 31) / 32)            // 1563 step2 work items
// HID=128, K=3, F_IN=7, effective features = 35 (+1 bias slot)
// Node feature rows: 8 x f16 = 16 B (one dwordx4 gather).
// adj entry (4 B): (peer << 16) | f16(w).  adjR keyed by r (peer=c), adjC by c.
//
// Session ledger (counter-verified lessons):
//  r1: nontemporal hints on scatter -> no change. WRITE_SIZE on atomic kernels
//      is coherent-point RMW traffic, not line eviction.
//  r2: 1.6M global RMWs == ~68us regardless of access pattern; csr_direct
//      sits at the same ~23G/s fabric rate. CSR build is done.
//  r3: 16-block LDS-scan scatter -> 210us (0.7% occupancy). Never again.
//  r4: k-outer phase B -> +52us (serialized weight loads vs FMAs). Keep the
//      per-wave wz[36]/wh[36] register form.
//  r5: slotted CSR (start = node<<6, one kernel): 791 -> 730us.
//  r6: branchless gather6: -30us only -> loop is NOT lane-latency-chain bound.
//  r7: coop mega-kernel == 24-dispatch loop (703 vs 700) -> launch gaps and
//      grid.sync are BOTH cheap; ~50us/step is real in-kernel time. Counter
//      rows for the coop kernel are replay-poisoned (47ms dur) - ignore them.
//  r8 (this): ISOLATED occupancy test: launch_bounds(256,8), grid 8/CU
//      (VGPR already 64 -> no spill). If <=650: latency/TLP-bound, push TLP.
//      If neutral: fixed-pipe throughput bound -> restructure gather pattern.

// ====== csr_direct: banded direct-slot scatter, the whole CSR build ========
__global__ __launch_bounds__(256) void csr_direct(
    const int* __restrict__ ei, const float* __restrict__ ew,
    int* __restrict__ nextR, int* __restrict__ nextC,
    unsigned* __restrict__ adjR, unsigned* __restrict__ adjC)
{
    int band = blockIdx.x & (NBAND - 1);
    int chunk = blockIdx.x >> 3;
    int lo = band * BAND, hi = lo + BAND;
    int stride = (gridDim.x >> 3) * 256;
    for (int e = chunk * 256 + threadIdx.x; e < Ee; e += stride) {
        int r = ei[e], c = ei[Ee + e];
        bool br = (r >= lo) & (r < hi);
        bool bc = (c >= lo) & (c < hi);
        if (br | bc) {
            unsigned wb = __half_as_ushort(__float2half(ew[e]));
            if (br) adjR[(r << 6) + atomicAdd(&nextR[r], 1)] = ((unsigned)c << 16) | wb;
            if (bc) adjC[(c << 6) + atomicAdd(&nextC[c], 1)] = ((unsigned)r << 16) | wb;
        }
    }
}

// ==== effective weights, layout [gate][k*128 + j], k=35 is the bias row ====
// f layout: [0..6]=X, [7..13]=Tx_o, [14..20]=Tx_i, [21..27]=T2_o, [28..34]=T2_i, [35]=1
__global__ __launch_bounds__(256) void weff_kernel(
    const float* __restrict__ Wz, const float* __restrict__ Wh,
    const float* __restrict__ bz, const float* __restrict__ bh,
    float* __restrict__ wzT, float* __restrict__ whT)
{
    int idx = blockIdx.x * 256 + threadIdx.x;
    if (idx >= 2 * 36 * 128) return;
    const float* W = (idx < 36 * 128) ? Wz : Wh;
    const float* B = (idx < 36 * 128) ? bz : bh;
    float* O       = (idx < 36 * 128) ? wzT : whT;
    int rem = idx % (36 * 128);
    int k = rem / 128, j = rem % 128;
    float v;
    if (k == 35) v = B[j];
    else {
        int p = k / 7, rr = k % 7;
        // W flat: ((d*3 + kk)*135 + rr)*128 + j
        if (p == 0)      v = W[(0 * 135 + rr) * 128 + j] + W[(3 * 135 + rr) * 128 + j];
        else if (p == 1) v = W[(1 * 135 + rr) * 128 + j];
        else if (p == 2) v = W[(4 * 135 + rr) * 128 + j];
        else if (p == 3) v = W[(2 * 135 + rr) * 128 + j];
        else             v = W[(5 * 135 + rr) * 128 + j];
    }
    O[k * 128 + j] = v;
}

// =================== init: Xh row (f16) and out column 0 ===================
__global__ __launch_bounds__(256) void init_kernel(
    const float* __restrict__ x, const float* __restrict__ env,
    const float* __restrict__ coords, __half* __restrict__ Xh,
    float* __restrict__ out)
{
    int i = blockIdx.x * 256 + threadIdx.x;
    if (i >= Nn) return;
    float xv = x[i * Tt];
    __half* r = Xh + (long)i * 8;
    r[0] = __float2half(xv);
    #pragma unroll
    for (int c = 0; c < 4; c++) r[1 + c] = __float2half(env[i * 48 + c * 12]);
    r[5] = __float2half(coords[i * 2 + 0]);
    r[6] = __float2half(coords[i * 2 + 1]);
    r[7] = __half(0.f);
    out[i * 13 + 0] = xv;
}

__device__ __forceinline__ void unpack8(const __half* p, float* v) {
    uint4 hv = *((const uint4*)p);
    float2 p0 = __half22float2(*(__half2*)&hv.x);
    float2 p1 = __half22float2(*(__half2*)&hv.y);
    float2 p2 = __half22float2(*(__half2*)&hv.z);
    float2 p3 = __half22float2(*(__half2*)&hv.w);
    v[0] = p0.x; v[1] = p0.y; v[2] = p1.x; v[3] = p1.y;
    v[4] = p2.x; v[5] = p2.y; v[6] = p3.x;
}

__device__ __forceinline__ void pack8(__half* p, const float* v) {
    __half2 q0 = __floats2half2_rn(v[0], v[1]);
    __half2 q1 = __floats2half2_rn(v[2], v[3]);
    __half2 q2 = __floats2half2_rn(v[4], v[5]);
    __half2 q3 = __floats2half2_rn(v[6], 0.f);
    uint4 st;
    st.x = *(unsigned*)&q0; st.y = *(unsigned*)&q1;
    st.z = *(unsigned*)&q2; st.w = *(unsigned*)&q3;
    *((uint4*)p) = st;
}

// accumulate a[0..6] += w * halfrow(hv)
__device__ __forceinline__ void acc7(float* a, float w, uint4 hv) {
    float2 p0 = __half22float2(*(__half2*)&hv.x);
    float2 p1 = __half22float2(*(__half2*)&hv.y);
    float2 p2 = __half22float2(*(__half2*)&hv.z);
    float2 p3 = __half22float2(*(__half2*)&hv.w);
    a[0] = fmaf(w, p0.x, a[0]); a[1] = fmaf(w, p0.y, a[1]);
    a[2] = fmaf(w, p1.x, a[2]); a[3] = fmaf(w, p1.y, a[3]);
    a[4] = fmaf(w, p2.x, a[4]); a[5] = fmaf(w, p2.y, a[5]);
    a[6] = fmaf(w, p3.x, a[6]);
}

__device__ __forceinline__ float wdec(unsigned ed) {
    return __half2float(__ushort_as_half((unsigned short)(ed & 0xffffu)));
}

// Branchless fixed-depth gather core (r6, kept): 6 slots stride 4 covers
// deg<=24 in one latency exposure; rare fallback loop beyond.
__device__ __forceinline__ void gather6(
    const unsigned* __restrict__ adj, const __half* __restrict__ src,
    int b, int k0, int e, float* a, float* sw)
{
    unsigned en[6];
    bool v[6];
    #pragma unroll
    for (int s = 0; s < 6; s++) {
        int k = k0 + 4 * s;
        v[s] = k < e;
        en[s] = adj[v[s] ? k : b];
    }
    uint4 rv[6];
    #pragma unroll
    for (int s = 0; s < 6; s++)
        rv[s] = *(const uint4*)(src + (long)(v[s] ? (en[s] >> 16) : 0u) * 8);
    #pragma unroll
    for (int s = 0; s < 6; s++) {
        float w = v[s] ? wdec(en[s]) : 0.f;
        acc7(a, w, rv[s]);
        if (sw) *sw += w;
    }
    for (int k = k0 + 24; k < e; k += 4) {    // rare: deg > 24
        unsigned ed = adj[k];
        uint4 r2 = *(const uint4*)(src + (long)(ed >> 16) * 8);
        float w = wdec(ed);
        acc7(a, w, r2);
        if (sw) *sw += w;
    }
}

// =============== phase bodies (shared by mega-kernel and fallback) =========
__device__ __forceinline__ void gather_phase(
    int tid,
    const int* __restrict__ cntR, const unsigned* __restrict__ adjR,
    const int* __restrict__ cntC, const unsigned* __restrict__ adjC,
    const __half* __restrict__ Xh,
    __half* __restrict__ TxoH, __half* __restrict__ TxiH,
    float* __restrict__ inv_out, float* __restrict__ inv_in)
{
    int node = tid >> 3;
    int dir = (tid >> 2) & 1, sub = tid & 3;
    const int*      cn  = dir ? cntC : cntR;
    const unsigned* adj = dir ? adjC : adjR;
    int b = node << 6, e = b + cn[node];
    float a[7] = {0.f, 0.f, 0.f, 0.f, 0.f, 0.f, 0.f};
    float sw = 0.f;
    gather6(adj, Xh, b, b + sub, e, a, &sw);
    #pragma unroll
    for (int m = 1; m <= 2; m <<= 1) {
        #pragma unroll
        for (int q = 0; q < 7; q++) a[q] += __shfl_xor(a[q], m);
        sw += __shfl_xor(sw, m);
    }
    if (sub == 0) {
        float inv = sw > 0.f ? 1.f / sw : 0.f;
        (dir ? inv_in : inv_out)[node] = inv;
        #pragma unroll
        for (int q = 0; q < 7; q++) a[q] *= inv;
        pack8((dir ? TxiH : TxoH) + (long)node * 8, a);
    }
}

__device__ __forceinline__ void step_phase(
    int wi, int t,
    const int* __restrict__ cntR, const unsigned* __restrict__ adjR,
    const int* __restrict__ cntC, const unsigned* __restrict__ adjC,
    const float* __restrict__ inv_out, const float* __restrict__ inv_in,
    const float* __restrict__ env, const float* __restrict__ night,
    const float* __restrict__ wzT, const float* __restrict__ whT,
    const float* __restrict__ linW, const float* __restrict__ linb,
    __half* __restrict__ Xh,
    const __half* __restrict__ TxoH, const __half* __restrict__ TxiH,
    float* __restrict__ out)
{
    __shared__ float f_s[32][36];
    __shared__ float part_s[2][32];
    int tid = threadIdx.x;
    int base = wi * 32;

    // ---- phase A: T2 for this item's 32 nodes, straight into LDS ----
    {
        int nl = tid >> 3;
        int dir = (tid >> 2) & 1, sub = tid & 3;
        int node = base + nl;
        int nc = node < Nn ? node : Nn - 1;   // clamp; output stores guarded
        const int*      cn  = dir ? cntC : cntR;
        const unsigned* adj = dir ? adjC : adjR;
        const __half*   src = dir ? TxiH : TxoH;
        int b = nc << 6, e = b + cn[nc];
        float a[7] = {0.f, 0.f, 0.f, 0.f, 0.f, 0.f, 0.f};
        gather6(adj, src, b, b + sub, e, a, nullptr);
        #pragma unroll
        for (int m = 1; m <= 2; m <<= 1) {
            #pragma unroll
            for (int q = 0; q < 7; q++) a[q] += __shfl_xor(a[q], m);
        }
        if (sub == 0) {
            float s2 = 2.f * (dir ? inv_in[nc] : inv_out[nc]);
            float xv[7], tx[7];
            unpack8(Xh + (long)nc * 8, xv);
            unpack8(src + (long)nc * 8, tx);     // own Tx row (dir-matched)
            #pragma unroll
            for (int q = 0; q < 7; q++) {
                f_s[nl][21 + 7 * dir + q] = fmaf(s2, a[q], -xv[q]);
                f_s[nl][7 + 7 * dir + q]  = tx[q];
            }
            if (dir == 0) {
                #pragma unroll
                for (int q = 0; q < 7; q++) f_s[nl][q] = xv[q];
                f_s[nl][35] = 1.f;
            }
        }
    }
    __syncthreads();

    // ---- phase B: dense 36x128x2 contraction + activations + output ----
    int lane = tid & 63;
    int wave = tid >> 6;
    int chSel = wave & 1;
    int ch = chSel * 64 + lane;
    int half_id = wave >> 1;
    float wz[36], wh[36];
    #pragma unroll
    for (int k = 0; k < 36; k++) wz[k] = wzT[k * 128 + ch];
    #pragma unroll
    for (int k = 0; k < 36; k++) wh[k] = whT[k * 128 + ch];
    float lw = linW[ch];
    float lb = linb[0];

    #pragma unroll 1
    for (int n = 0; n < 16; n++) {
        int ni = half_id * 16 + n;
        const float4* fv = (const float4*)f_s[ni];   // broadcast reads
        float hz = 0.f, hh = 0.f;
        #pragma unroll
        for (int q = 0; q < 9; q++) {
            float4 fq = fv[q];
            hz = fmaf(fq.x, wz[q*4+0], hz); hh = fmaf(fq.x, wh[q*4+0], hh);
            hz = fmaf(fq.y, wz[q*4+1], hz); hh = fmaf(fq.y, wh[q*4+1], hh);
            hz = fmaf(fq.z, wz[q*4+2], hz); hh = fmaf(fq.z, wh[q*4+2], hh);
            hz = fmaf(fq.w, wz[q*4+3], hz); hh = fmaf(fq.w, wh[q*4+3], hh);
        }
        float z  = 1.f / (1.f + __expf(-hz));
        float e2 = __expf(2.f * hh);
        float ht = 1.f - 2.f / (e2 + 1.f);           // tanh
        float v = fmaxf((1.f - z) * ht, 0.f) * lw;   // (1-Z)*H~, relu, lin
        v += __shfl_xor(v, 1);  v += __shfl_xor(v, 2);  v += __shfl_xor(v, 4);
        v += __shfl_xor(v, 8);  v += __shfl_xor(v, 16); v += __shfl_xor(v, 32);
        if (lane == 0) part_s[chSel][ni] = v;
    }
    __syncthreads();
    if (tid < 32) {
        int node = base + tid;
        if (node < Nn) {
            float o = part_s[0][tid] + part_s[1][tid] + lb;
            o *= night[(long)node * 13 + t + 1];
            out[(long)node * 13 + t + 1] = o;
            if (t + 1 < Tt) {
                __half* xr = Xh + (long)node * 8;
                xr[0] = __float2half(o);
                #pragma unroll
                for (int c = 0; c < 4; c++)
                    xr[1 + c] = __float2half(env[(long)node * 48 + c * 12 + t + 1]);
            }
        }
    }
}

// ============ cooperative mega-kernel: all 12 steps, 23 grid syncs =========
// r8: launch_bounds(256,8) -> VGPR capped at 64 (r7 already compiled to 64),
// 8 blocks/CU resident -> 32 waves/CU (was 16). Isolated TLP experiment.
__global__ __launch_bounds__(256, 8) void loop_kernel(
    const int* __restrict__ cntR, const unsigned* __restrict__ adjR,
    const int* __restrict__ cntC, const unsigned* __restrict__ adjC,
    float* __restrict__ inv_out, float* __restrict__ inv_in,
    const float* __restrict__ env, const float* __restrict__ night,
    const float* __restrict__ wzT, const float* __restrict__ whT,
    const float* __restrict__ linW, const float* __restrict__ linb,
    __half* __restrict__ Xh, __half* __restrict__ TxoH, __half* __restrict__ TxiH,
    float* __restrict__ out, int* __restrict__ ctr)
{
    cg::grid_group grid = cg::this_grid();
    __shared__ int item_s;
    for (int t = 0; t < Tt; t++) {
        // ---- phase G: Tx gather over Nn*8 thread-items, 256 per chunk ----
        for (;;) {
            if (threadIdx.x == 0) item_s = atomicAdd(&ctr[t], 1);
            __syncthreads();
            int chunk = item_s;
            __syncthreads();              // all read before next overwrite
            if (chunk >= NCHUNK) break;   // uniform
            int tid = chunk * 256 + threadIdx.x;
            if (tid < Nn * 8)
                gather_phase(tid, cntR, adjR, cntC, adjC, Xh, TxoH, TxiH,
                             inv_out, inv_in);
        }
        __threadfence();
        grid.sync();
        // ---- phase S: T2 + dense over 1563 32-node items ----
        for (;;) {
            if (threadIdx.x == 0) item_s = atomicAdd(&ctr[12 + t], 1);
            __syncthreads();
            int wi = item_s;
            __syncthreads();
            if (wi >= NWI) break;         // uniform
            step_phase(wi, t, cntR, adjR, cntC, adjC, inv_out, inv_in,
                       env, night, wzT, whT, linW, linb, Xh, TxoH, TxiH, out);
        }
        __threadfence();
        grid.sync();
    }
}

// ================== fallback wrappers (r6 structure, proven) ===============
__global__ __launch_bounds__(256) void gather1_kernel(
    const int* __restrict__ cntR, const unsigned* __restrict__ adjR,
    const int* __restrict__ cntC, const unsigned* __restrict__ adjC,
    const __half* __restrict__ Xh,
    __half* __restrict__ TxoH, __half* __restrict__ TxiH,
    float* __restrict__ inv_out, float* __restrict__ inv_in)
{
    int tid = blockIdx.x * 256 + threadIdx.x;
    if (tid >= Nn * 8) return;
    gather_phase(tid, cntR, adjR, cntC, adjC, Xh, TxoH, TxiH, inv_out, inv_in);
}

__global__ __launch_bounds__(256) void step2_kernel(
    const int* __restrict__ cntR, const unsigned* __restrict__ adjR,
    const int* __restrict__ cntC, const unsigned* __restrict__ adjC,
    const float* __restrict__ inv_out, const float* __restrict__ inv_in,
    const float* __restrict__ env, const float* __restrict__ night,
    const float* __restrict__ wzT, const float* __restrict__ whT,
    const float* __restrict__ linW, const float* __restrict__ linb,
    __half* __restrict__ Xh,
    const __half* __restrict__ TxoH, const __half* __restrict__ TxiH,
    float* __restrict__ out, int t)
{
    step_phase(blockIdx.x, t, cntR, adjR, cntC, adjC, inv_out, inv_in,
               env, night, wzT, whT, linW, linb, Xh, TxoH, TxiH, out);
}

extern "C" void kernel_launch(void* const* d_in, const int* in_sizes, int n_in,
                              void* d_out, int out_size, void* d_ws, size_t ws_size,
                              hipStream_t stream) {
    const float* x      = (const float*)d_in[0];
    const float* env    = (const float*)d_in[1];
    const float* coords = (const float*)d_in[2];
    const int*   ei     = (const int*)d_in[3];
    const float* ew     = (const float*)d_in[4];
    const float* night  = (const float*)d_in[5];
    const float* Wz     = (const float*)d_in[6];
    const float* bz     = (const float*)d_in[7];
    // d_in[8]=Wr, d_in[9]=br unused (R gate never affects output)
    const float* Wh     = (const float*)d_in[10];
    const float* bh     = (const float*)d_in[11];
    const float* linW   = (const float*)d_in[12];
    const float* linb   = (const float*)d_in[13];
    float* out = (float*)d_out;

    float* w = (float*)d_ws;
    float* wzT     = w;                     // 36*128
    float* whT     = w + 4608;
    float* inv_out = w + 9216;              // N
    float* inv_in  = w + 59216;
    __half* Xh   = (__half*)(w + 109216);   // N x 8 halves (16B-aligned offsets)
    __half* TxoH = (__half*)(w + 309216);
    __half* TxiH = (__half*)(w + 509216);
    int* nextR   = (int*)(w + 709216);      // N; doubles as cntR after scatter
    int* nextC   = nextR + 50000;           // N; doubles as cntC
    int* ctr     = (int*)(w + 809216);      // 64 ints: [0..11]=G, [12..23]=S
    unsigned* adjR = (unsigned*)(w + 809280);    // N*64 slots x 4B = 12.8 MB
    unsigned* adjC = adjR + Nn * CAP;            // 12.8 MB; end ~ 28.8 MB

    // ---- CSR build: single direct-slot scatter + counter zeroing ----
    hipMemsetAsync(nextR, 0, (2 * Nn + 64) * sizeof(int), stream);
    csr_direct<<<8 * 256, 256, 0, stream>>>(ei, ew, nextR, nextC, adjR, adjC);

    weff_kernel<<<(2 * 36 * 128 + 255) / 256, 256, 0, stream>>>(Wz, Wh, bz, bh, wzT, whT);
    init_kernel<<<(Nn + 255) / 256, 256, 0, stream>>>(x, env, coords, Xh, out);

    // ---- time loop: cooperative mega-kernel, fallback to r6 loop ----
    static int coopGrid = -2;   // -2 uninit, -1 unavailable
    if (coopGrid == -2) {
        hipDeviceProp_t prop{};
        if (hipGetDeviceProperties(&prop, 0) == hipSuccess &&
            prop.cooperativeLaunch && prop.multiProcessorCount > 0) {
            coopGrid = 8 * prop.multiProcessorCount;       // launch_bounds(256,8)
            if (coopGrid > 2048) coopGrid = 2048;
        } else coopGrid = -1;
    }
    bool did_coop = false;
    if (coopGrid > 0) {
        void* params[] = { (void*)&nextR, (void*)&adjR, (void*)&nextC, (void*)&adjC,
                           (void*)&inv_out, (void*)&inv_in, (void*)&env, (void*)&night,
                           (void*)&wzT, (void*)&whT, (void*)&linW, (void*)&linb,
                           (void*)&Xh, (void*)&TxoH, (void*)&TxiH, (void*)&out,
                           (void*)&ctr };
        if (hipLaunchCooperativeKernel((const void*)loop_kernel, dim3(coopGrid),
                                       dim3(256), params, 0, stream) == hipSuccess)
            did_coop = true;
        else
            coopGrid = -1;   // don't retry on later calls
    }
    if (!did_coop) {
        for (int t = 0; t < Tt; t++) {
            gather1_kernel<<<(Nn * 8 + 255) / 256, 256, 0, stream>>>(
                nextR, adjR, nextC, adjC, Xh, TxoH, TxiH, inv_out, inv_in);
            step2_kernel<<<(Nn + 31) / 32, 256, 0, stream>>>(
                nextR, adjR, nextC, adjC, inv_out, inv_in,
                env, night, wzT, whT, linW, linb, Xh, TxoH, TxiH, out, t);
        }
    }
}

// Round 9
// 699.151 us; speedup vs baseline: 1.0062x; 1.0035x over previous
//
#include <hip/hip_runtime.h>
#include <hip/hip_fp16.h>

#define Nn 50000
#define Ee 800000
#define Tt 12
#define NBAND 8
#define BAND 6250        // Nn / NBAND exactly
#define CAP 64           // fixed adj slots per node; P(Poisson(16) >= 64) ~ 8e-20
#define NCHUNK ((Nn * 8 + 255) / 256)   // 1563 gather chunks (256 thr each)
#define NWI ((Nn + 31) / 32)            // 1563 step2 work items
#define BPB 196                          // blocks per band: 8*196 = 1568 >= 1563
// HID=128, K=3, F_IN=7, effective features = 35 (+1 bias slot)
// Node feature rows: 8 x f16 = 16 B (one dwordx4 gather).
// adj entry (4 B): (peer << 16) | f16(w).  adjR keyed by r (peer=c), adjC by c.
//
// Session ledger (counter-verified lessons):
//  r1: nontemporal hints on scatter -> no change. WRITE_SIZE on atomic kernels
//      is coherent-point RMW traffic, not line eviction.
//  r2: 1.6M global RMWs == ~68us regardless of access pattern; csr_direct
//      sits at the same ~23G/s fabric rate. CSR build is done.
//  r3: 16-block LDS-scan scatter -> 210us (0.7% occupancy). Never again.
//  r4: k-outer phase B -> +52us (serialized weight loads vs FMAs). Keep the
//      per-wave wz[36]/wh[36] register form.
//  r5: slotted CSR (start = node<<6, one kernel): 791 -> 730us.
//  r6: branchless gather6: -30us only -> loop is NOT lane-latency-chain bound.
//  r7: coop mega-kernel == 24-dispatch loop (703 vs 700) -> launch gaps and
//      grid.sync are BOTH cheap; ~50us/step is real in-kernel time.
//  r8: 2x occupancy -> exactly neutral, AND whole-loop FETCH 1.5->4.3GB,
//      WRITE 178->878MB. Diagnosis: per-XCD L2 capacity thrash (~10MB working
//      set vs 4MB L2, work spread over all XCDs); more waves = more thrash.
//  r9 (this): band-affine static mapping (blockIdx%8 = band = XCD, same
//      residue trick as csr_direct) so each XCD's L2 holds its band's adj
//      slice + shared Xh/Tx replicas (~4MB total). Phase bodies unchanged.

// ====== csr_direct: banded direct-slot scatter, the whole CSR build ========
__global__ __launch_bounds__(256) void csr_direct(
    const int* __restrict__ ei, const float* __restrict__ ew,
    int* __restrict__ nextR, int* __restrict__ nextC,
    unsigned* __restrict__ adjR, unsigned* __restrict__ adjC)
{
    int band = blockIdx.x & (NBAND - 1);
    int chunk = blockIdx.x >> 3;
    int lo = band * BAND, hi = lo + BAND;
    int stride = (gridDim.x >> 3) * 256;
    for (int e = chunk * 256 + threadIdx.x; e < Ee; e += stride) {
        int r = ei[e], c = ei[Ee + e];
        bool br = (r >= lo) & (r < hi);
        bool bc = (c >= lo) & (c < hi);
        if (br | bc) {
            unsigned wb = __half_as_ushort(__float2half(ew[e]));
            if (br) adjR[(r << 6) + atomicAdd(&nextR[r], 1)] = ((unsigned)c << 16) | wb;
            if (bc) adjC[(c << 6) + atomicAdd(&nextC[c], 1)] = ((unsigned)r << 16) | wb;
        }
    }
}

// ==== effective weights, layout [gate][k*128 + j], k=35 is the bias row ====
// f layout: [0..6]=X, [7..13]=Tx_o, [14..20]=Tx_i, [21..27]=T2_o, [28..34]=T2_i, [35]=1
__global__ __launch_bounds__(256) void weff_kernel(
    const float* __restrict__ Wz, const float* __restrict__ Wh,
    const float* __restrict__ bz, const float* __restrict__ bh,
    float* __restrict__ wzT, float* __restrict__ whT)
{
    int idx = blockIdx.x * 256 + threadIdx.x;
    if (idx >= 2 * 36 * 128) return;
    const float* W = (idx < 36 * 128) ? Wz : Wh;
    const float* B = (idx < 36 * 128) ? bz : bh;
    float* O       = (idx < 36 * 128) ? wzT : whT;
    int rem = idx % (36 * 128);
    int k = rem / 128, j = rem % 128;
    float v;
    if (k == 35) v = B[j];
    else {
        int p = k / 7, rr = k % 7;
        // W flat: ((d*3 + kk)*135 + rr)*128 + j
        if (p == 0)      v = W[(0 * 135 + rr) * 128 + j] + W[(3 * 135 + rr) * 128 + j];
        else if (p == 1) v = W[(1 * 135 + rr) * 128 + j];
        else if (p == 2) v = W[(4 * 135 + rr) * 128 + j];
        else if (p == 3) v = W[(2 * 135 + rr) * 128 + j];
        else             v = W[(5 * 135 + rr) * 128 + j];
    }
    O[k * 128 + j] = v;
}

// =================== init: Xh row (f16) and out column 0 ===================
__global__ __launch_bounds__(256) void init_kernel(
    const float* __restrict__ x, const float* __restrict__ env,
    const float* __restrict__ coords, __half* __restrict__ Xh,
    float* __restrict__ out)
{
    int i = blockIdx.x * 256 + threadIdx.x;
    if (i >= Nn) return;
    float xv = x[i * Tt];
    __half* r = Xh + (long)i * 8;
    r[0] = __float2half(xv);
    #pragma unroll
    for (int c = 0; c < 4; c++) r[1 + c] = __float2half(env[i * 48 + c * 12]);
    r[5] = __float2half(coords[i * 2 + 0]);
    r[6] = __float2half(coords[i * 2 + 1]);
    r[7] = __half(0.f);
    out[i * 13 + 0] = xv;
}

__device__ __forceinline__ void unpack8(const __half* p, float* v) {
    uint4 hv = *((const uint4*)p);
    float2 p0 = __half22float2(*(__half2*)&hv.x);
    float2 p1 = __half22float2(*(__half2*)&hv.y);
    float2 p2 = __half22float2(*(__half2*)&hv.z);
    float2 p3 = __half22float2(*(__half2*)&hv.w);
    v[0] = p0.x; v[1] = p0.y; v[2] = p1.x; v[3] = p1.y;
    v[4] = p2.x; v[5] = p2.y; v[6] = p3.x;
}

__device__ __forceinline__ void pack8(__half* p, const float* v) {
    __half2 q0 = __floats2half2_rn(v[0], v[1]);
    __half2 q1 = __floats2half2_rn(v[2], v[3]);
    __half2 q2 = __floats2half2_rn(v[4], v[5]);
    __half2 q3 = __floats2half2_rn(v[6], 0.f);
    uint4 st;
    st.x = *(unsigned*)&q0; st.y = *(unsigned*)&q1;
    st.z = *(unsigned*)&q2; st.w = *(unsigned*)&q3;
    *((uint4*)p) = st;
}

// accumulate a[0..6] += w * halfrow(hv)
__device__ __forceinline__ void acc7(float* a, float w, uint4 hv) {
    float2 p0 = __half22float2(*(__half2*)&hv.x);
    float2 p1 = __half22float2(*(__half2*)&hv.y);
    float2 p2 = __half22float2(*(__half2*)&hv.z);
    float2 p3 = __half22float2(*(__half2*)&hv.w);
    a[0] = fmaf(w, p0.x, a[0]); a[1] = fmaf(w, p0.y, a[1]);
    a[2] = fmaf(w, p1.x, a[2]); a[3] = fmaf(w, p1.y, a[3]);
    a[4] = fmaf(w, p2.x, a[4]); a[5] = fmaf(w, p2.y, a[5]);
    a[6] = fmaf(w, p3.x, a[6]);
}

__device__ __forceinline__ float wdec(unsigned ed) {
    return __half2float(__ushort_as_half((unsigned short)(ed & 0xffffu)));
}

// Branchless fixed-depth gather core (r6, kept): 6 slots stride 4 covers
// deg<=24 in one latency exposure; rare fallback loop beyond.
__device__ __forceinline__ void gather6(
    const unsigned* __restrict__ adj, const __half* __restrict__ src,
    int b, int k0, int e, float* a, float* sw)
{
    unsigned en[6];
    bool v[6];
    #pragma unroll
    for (int s = 0; s < 6; s++) {
        int k = k0 + 4 * s;
        v[s] = k < e;
        en[s] = adj[v[s] ? k : b];
    }
    uint4 rv[6];
    #pragma unroll
    for (int s = 0; s < 6; s++)
        rv[s] = *(const uint4*)(src + (long)(v[s] ? (en[s] >> 16) : 0u) * 8);
    #pragma unroll
    for (int s = 0; s < 6; s++) {
        float w = v[s] ? wdec(en[s]) : 0.f;
        acc7(a, w, rv[s]);
        if (sw) *sw += w;
    }
    for (int k = k0 + 24; k < e; k += 4) {    // rare: deg > 24
        unsigned ed = adj[k];
        uint4 r2 = *(const uint4*)(src + (long)(ed >> 16) * 8);
        float w = wdec(ed);
        acc7(a, w, r2);
        if (sw) *sw += w;
    }
}

// ============== gather pass 1: Tx = inv * segsum(w * Xh[src]) ==============
// Band-affine: blockIdx%8 = band = XCD; chunk = band*BPB + blockIdx/8.
// XCD beta's L2 then holds its band's adj slice + Xh replica.
__global__ __launch_bounds__(256) void gather1_kernel(
    const int* __restrict__ cntR, const unsigned* __restrict__ adjR,
    const int* __restrict__ cntC, const unsigned* __restrict__ adjC,
    const __half* __restrict__ Xh,
    __half* __restrict__ TxoH, __half* __restrict__ TxiH,
    float* __restrict__ inv_out, float* __restrict__ inv_in)
{
    int beta = blockIdx.x & (NBAND - 1);
    int j = blockIdx.x >> 3;
    int chunk = beta * BPB + j;
    if (chunk >= NCHUNK) return;
    int tid = chunk * 256 + threadIdx.x;
    if (tid >= Nn * 8) return;
    int node = tid >> 3;
    int dir = (tid >> 2) & 1, sub = tid & 3;
    const int*      cn  = dir ? cntC : cntR;
    const unsigned* adj = dir ? adjC : adjR;
    int b = node << 6, e = b + cn[node];
    float a[7] = {0.f, 0.f, 0.f, 0.f, 0.f, 0.f, 0.f};
    float sw = 0.f;
    gather6(adj, Xh, b, b + sub, e, a, &sw);
    #pragma unroll
    for (int m = 1; m <= 2; m <<= 1) {
        #pragma unroll
        for (int q = 0; q < 7; q++) a[q] += __shfl_xor(a[q], m);
        sw += __shfl_xor(sw, m);
    }
    if (sub == 0) {
        float inv = sw > 0.f ? 1.f / sw : 0.f;
        (dir ? inv_in : inv_out)[node] = inv;
        #pragma unroll
        for (int q = 0; q < 7; q++) a[q] *= inv;
        pack8((dir ? TxiH : TxoH) + (long)node * 8, a);
    }
}

// ====== fused step2: second-order propagation (into LDS, fp32) + dense =====
// Band-affine: wi = (blockIdx%8)*BPB + blockIdx/8. Phase bodies = r6 proven.
__global__ __launch_bounds__(256) void step2_kernel(
    const int* __restrict__ cntR, const unsigned* __restrict__ adjR,
    const int* __restrict__ cntC, const unsigned* __restrict__ adjC,
    const float* __restrict__ inv_out, const float* __restrict__ inv_in,
    const float* __restrict__ env, const float* __restrict__ night,
    const float* __restrict__ wzT, const float* __restrict__ whT,
    const float* __restrict__ linW, const float* __restrict__ linb,
    __half* __restrict__ Xh,
    const __half* __restrict__ TxoH, const __half* __restrict__ TxiH,
    float* __restrict__ out, int t)
{
    int beta = blockIdx.x & (NBAND - 1);
    int j = blockIdx.x >> 3;
    int wi = beta * BPB + j;
    if (wi >= NWI) return;

    __shared__ float f_s[32][36];
    __shared__ float part_s[2][32];
    int tid = threadIdx.x;
    int base = wi * 32;

    // ---- phase A: T2 for this item's 32 nodes, straight into LDS ----
    {
        int nl = tid >> 3;
        int dir = (tid >> 2) & 1, sub = tid & 3;
        int node = base + nl;
        int nc = node < Nn ? node : Nn - 1;   // clamp; output stores guarded
        const int*      cn  = dir ? cntC : cntR;
        const unsigned* adj = dir ? adjC : adjR;
        const __half*   src = dir ? TxiH : TxoH;
        int b = nc << 6, e = b + cn[nc];
        float a[7] = {0.f, 0.f, 0.f, 0.f, 0.f, 0.f, 0.f};
        gather6(adj, src, b, b + sub, e, a, nullptr);
        #pragma unroll
        for (int m = 1; m <= 2; m <<= 1) {
            #pragma unroll
            for (int q = 0; q < 7; q++) a[q] += __shfl_xor(a[q], m);
        }
        if (sub == 0) {
            float s2 = 2.f * (dir ? inv_in[nc] : inv_out[nc]);
            float xv[7], tx[7];
            unpack8(Xh + (long)nc * 8, xv);
            unpack8(src + (long)nc * 8, tx);     // own Tx row (dir-matched)
            #pragma unroll
            for (int q = 0; q < 7; q++) {
                f_s[nl][21 + 7 * dir + q] = fmaf(s2, a[q], -xv[q]);
                f_s[nl][7 + 7 * dir + q]  = tx[q];
            }
            if (dir == 0) {
                #pragma unroll
                for (int q = 0; q < 7; q++) f_s[nl][q] = xv[q];
                f_s[nl][35] = 1.f;
            }
        }
    }
    __syncthreads();

    // ---- phase B: dense 36x128x2 contraction + activations + output ----
    int lane = tid & 63;
    int wave = tid >> 6;
    int chSel = wave & 1;
    int ch = chSel * 64 + lane;
    int half_id = wave >> 1;
    float wz[36], wh[36];
    #pragma unroll
    for (int k = 0; k < 36; k++) wz[k] = wzT[k * 128 + ch];
    #pragma unroll
    for (int k = 0; k < 36; k++) wh[k] = whT[k * 128 + ch];
    float lw = linW[ch];
    float lb = linb[0];

    #pragma unroll 1
    for (int n = 0; n < 16; n++) {
        int ni = half_id * 16 + n;
        const float4* fv = (const float4*)f_s[ni];   // broadcast reads
        float hz = 0.f, hh = 0.f;
        #pragma unroll
        for (int q = 0; q < 9; q++) {
            float4 fq = fv[q];
            hz = fmaf(fq.x, wz[q*4+0], hz); hh = fmaf(fq.x, wh[q*4+0], hh);
            hz = fmaf(fq.y, wz[q*4+1], hz); hh = fmaf(fq.y, wh[q*4+1], hh);
            hz = fmaf(fq.z, wz[q*4+2], hz); hh = fmaf(fq.z, wh[q*4+2], hh);
            hz = fmaf(fq.w, wz[q*4+3], hz); hh = fmaf(fq.w, wh[q*4+3], hh);
        }
        float z  = 1.f / (1.f + __expf(-hz));
        float e2 = __expf(2.f * hh);
        float ht = 1.f - 2.f / (e2 + 1.f);           // tanh
        float v = fmaxf((1.f - z) * ht, 0.f) * lw;   // (1-Z)*H~, relu, lin
        v += __shfl_xor(v, 1);  v += __shfl_xor(v, 2);  v += __shfl_xor(v, 4);
        v += __shfl_xor(v, 8);  v += __shfl_xor(v, 16); v += __shfl_xor(v, 32);
        if (lane == 0) part_s[chSel][ni] = v;
    }
    __syncthreads();
    if (tid < 32) {
        int node = base + tid;
        if (node < Nn) {
            float o = part_s[0][tid] + part_s[1][tid] + lb;
            o *= night[(long)node * 13 + t + 1];
            out[(long)node * 13 + t + 1] = o;
            if (t + 1 < Tt) {
                __half* xr = Xh + (long)node * 8;
                xr[0] = __float2half(o);
                #pragma unroll
                for (int c = 0; c < 4; c++)
                    xr[1 + c] = __float2half(env[(long)node * 48 + c * 12 + t + 1]);
            }
        }
    }
}

extern "C" void kernel_launch(void* const* d_in, const int* in_sizes, int n_in,
                              void* d_out, int out_size, void* d_ws, size_t ws_size,
                              hipStream_t stream) {
    const float* x      = (const float*)d_in[0];
    const float* env    = (const float*)d_in[1];
    const float* coords = (const float*)d_in[2];
    const int*   ei     = (const int*)d_in[3];
    const float* ew     = (const float*)d_in[4];
    const float* night  = (const float*)d_in[5];
    const float* Wz     = (const float*)d_in[6];
    const float* bz     = (const float*)d_in[7];
    // d_in[8]=Wr, d_in[9]=br unused (R gate never affects output)
    const float* Wh     = (const float*)d_in[10];
    const float* bh     = (const float*)d_in[11];
    const float* linW   = (const float*)d_in[12];
    const float* linb   = (const float*)d_in[13];
    float* out = (float*)d_out;

    float* w = (float*)d_ws;
    float* wzT     = w;                     // 36*128
    float* whT     = w + 4608;
    float* inv_out = w + 9216;              // N
    float* inv_in  = w + 59216;
    __half* Xh   = (__half*)(w + 109216);   // N x 8 halves (16B-aligned offsets)
    __half* TxoH = (__half*)(w + 309216);
    __half* TxiH = (__half*)(w + 509216);
    int* nextR   = (int*)(w + 709216);      // N; doubles as cntR after scatter
    int* nextC   = nextR + 50000;           // N; doubles as cntC
    unsigned* adjR = (unsigned*)(w + 809280);    // N*64 slots x 4B = 12.8 MB
    unsigned* adjC = adjR + Nn * CAP;            // 12.8 MB; end ~ 28.8 MB

    // ---- CSR build: single direct-slot scatter (1.6M RMWs total) ----
    hipMemsetAsync(nextR, 0, 2 * Nn * sizeof(int), stream);
    csr_direct<<<8 * 256, 256, 0, stream>>>(ei, ew, nextR, nextC, adjR, adjC);

    weff_kernel<<<(2 * 36 * 128 + 255) / 256, 256, 0, stream>>>(Wz, Wh, bz, bh, wzT, whT);
    init_kernel<<<(Nn + 255) / 256, 256, 0, stream>>>(x, env, coords, Xh, out);

    // ---- time loop: 24 dispatches, band-affine block mapping ----
    for (int t = 0; t < Tt; t++) {
        gather1_kernel<<<8 * BPB, 256, 0, stream>>>(
            nextR, adjR, nextC, adjC, Xh, TxoH, TxiH, inv_out, inv_in);
        step2_kernel<<<8 * BPB, 256, 0, stream>>>(
            nextR, adjR, nextC, adjC, inv_out, inv_in,
            env, night, wzT, whT, linW, linb, Xh, TxoH, TxiH, out, t);
    }
}